// Round 3
// baseline (534.322 us; speedup 1.0000x reference)
//
#include <hip/hip_runtime.h>

// out[b,k,n,m] = clip(exp(-0.1*sqrt(max(|An|^2 - 2 An.Am + |Am|^2, 1e-6))), 0, 1)
// x: (8,64,512,16) fp32, msk: (8,64,512,1) fp32, out: (8,64,512,512,1) fp32 (512 MiB).
//
// v4: plain write-back stores (single change vs v3). Evidence: v1/v3 both ~185 us
// kernel vs 85 us write floor at 6.3 TB/s (= what the harness's fillBuffer with
// PLAIN stores achieves on this very buffer); contiguity retile (v3) moved
// nothing, so the NT store path is the prime suspect: it couples store
// retirement to HBM drain (no L2 elasticity) and/or ceilings below write-back.
// We write full 128B lines per wave, so plain stores incur no read-for-ownership
// (fill shows FETCH_SIZE~0 on a 2 GiB write) and L2 acts as an elastic buffer,
// letting compute overlap the drain.
//  - Block = 64 rows x 512 cols of one slice -> output region is one CONTIGUOUS
//    128 KiB stream; each f32x4 store instruction writes 1024 B contiguous.
//  - f32 VALU Gram, 8x8 register tile, 1024 FMA/thread.
//  - Row fragments broadcast from LDS; norms folded into staging (one sync).
//  - grid(512,8): linear id == slice (mod 8) -> per-slice XCD affinity.

typedef float f32x4 __attribute__((ext_vector_type(4)));

#define NEG_DIST_LOG2E (-0.14426950408889634f)  // -0.1 * log2(e)
#define EPS_F 1e-6f
#define LDM 516   // 512 + 4 pad
#define LDN 68    // 64 + 4 pad

__global__ __launch_bounds__(512) void node_pair_gaussian_kernel(
    const float* __restrict__ x,    // (512 slices, 512 nodes, 16 f)
    const float* __restrict__ msk,  // (512 slices, 512 nodes)
    float* __restrict__ out)        // (512 slices, 512, 512)
{
    __shared__ __align__(16) float lds_m[16][LDM];  // full slice, [f][node]
    __shared__ __align__(16) float lds_n[16][LDN];  // 64-row tile, [f][node]
    __shared__ __align__(16) float na_m[512];
    __shared__ __align__(16) float na_n[64];

    const int tid   = threadIdx.x;       // 0..511
    const int slice = blockIdx.x;        // 0..511
    const int r0    = blockIdx.y << 6;   // row tile base: 0..448

    const float* xs = x   + (size_t)slice * (512 * 16);
    const float* ms = msk + (size_t)slice * 512;

    // ---- Stage full slice (col operand) transposed [f][node], masked; fold in
    //      squared-norm computation via 4-lane shuffle reduce ----
    #pragma unroll
    for (int it = 0; it < 4; ++it) {
        const int c    = tid + it * 512;          // 0..2047 = 512 nodes x 4 chunks
        const int node = c >> 2;
        const int f4   = (c & 3) * 4;
        const f32x4 v  = *(const f32x4*)(xs + (size_t)c * 4);  // coalesced
        const float mm = ms[node];
        lds_m[f4 + 0][node] = v.x * mm;
        lds_m[f4 + 1][node] = v.y * mm;
        lds_m[f4 + 2][node] = v.z * mm;
        lds_m[f4 + 3][node] = v.w * mm;
        // partial |A|^2 for this 4-feature chunk; 4 adjacent lanes hold one node
        float p = (v.x * v.x + v.y * v.y + v.z * v.z + v.w * v.w) * (mm * mm);
        p += __shfl_xor(p, 1);
        p += __shfl_xor(p, 2);
        if ((tid & 3) == 0) na_m[node] = p;
    }
    // ---- Stage 64-row tile (row operand) the same way ----
    if (tid < 256) {
        const int node = tid >> 2;                // 0..63
        const int f4   = (tid & 3) * 4;
        const f32x4 v  = *(const f32x4*)(xs + (size_t)(r0 + node) * 16 + f4);
        const float mm = ms[r0 + node];
        lds_n[f4 + 0][node] = v.x * mm;
        lds_n[f4 + 1][node] = v.y * mm;
        lds_n[f4 + 2][node] = v.z * mm;
        lds_n[f4 + 3][node] = v.w * mm;
        float p = (v.x * v.x + v.y * v.y + v.z * v.z + v.w * v.w) * (mm * mm);
        p += __shfl_xor(p, 1);
        p += __shfl_xor(p, 2);
        if ((tid & 3) == 0) na_n[node] = p;
    }
    __syncthreads();

    // ---- 8x8 register-tile Gram: wave owns 8 consecutive rows, lane owns
    //      cols lane*4..+3 and 256+lane*4..+3 ----
    const int lane = tid & 63;
    const int w8   = (tid >> 6) << 3;    // wave*8: this wave's row base (0..56)

    float acc[8][8];
    #pragma unroll
    for (int i = 0; i < 8; ++i)
        #pragma unroll
        for (int j = 0; j < 8; ++j) acc[i][j] = 0.0f;

    #pragma unroll
    for (int f = 0; f < 16; ++f) {
        const f32x4 a0 = *(const f32x4*)&lds_n[f][w8];        // broadcast reads
        const f32x4 a1 = *(const f32x4*)&lds_n[f][w8 + 4];
        const f32x4 b0 = *(const f32x4*)&lds_m[f][lane * 4];        // strided
        const f32x4 b1 = *(const f32x4*)&lds_m[f][256 + lane * 4];
        const float an[8] = {a0.x, a0.y, a0.z, a0.w, a1.x, a1.y, a1.z, a1.w};
        const float am[8] = {b0.x, b0.y, b0.z, b0.w, b1.x, b1.y, b1.z, b1.w};
        #pragma unroll
        for (int i = 0; i < 8; ++i)
            #pragma unroll
            for (int j = 0; j < 8; ++j)
                acc[i][j] = fmaf(an[i], am[j], acc[i][j]);
    }

    const f32x4 nn0 = *(const f32x4*)&na_n[w8];               // broadcast
    const f32x4 nn1 = *(const f32x4*)&na_n[w8 + 4];
    const f32x4 nm0 = *(const f32x4*)&na_m[lane * 4];
    const f32x4 nm1 = *(const f32x4*)&na_m[256 + lane * 4];
    const float nn[8] = {nn0.x, nn0.y, nn0.z, nn0.w, nn1.x, nn1.y, nn1.z, nn1.w};
    const float nm[8] = {nm0.x, nm0.y, nm0.z, nm0.w, nm1.x, nm1.y, nm1.z, nm1.w};

    // Block output = out[slice][r0 : r0+64][:], one contiguous 128 KiB region.
    float* outs = out + (size_t)slice * (512 * 512) + (size_t)r0 * 512;

    // ---- Fused epilogue + plain write-back stores: each instruction = 1024 B
    //      contiguous (lane-consecutive 16 B), wave covers 8 full 2 KiB rows ----
    #pragma unroll
    for (int i = 0; i < 8; ++i) {
        float r[8];
        #pragma unroll
        for (int j = 0; j < 8; ++j) {
            float s = fmaf(-2.0f, acc[i][j], nn[i] + nm[j]);
            s = fmaxf(s, EPS_F);
            const float d = __builtin_amdgcn_sqrtf(s);
            const float e = __builtin_amdgcn_exp2f(d * NEG_DIST_LOG2E);
            r[j] = fminf(e, 1.0f);   // CLIP_LOW=0 implied: e > 0 always
        }
        f32x4 w0 = {r[0], r[1], r[2], r[3]};
        f32x4 w1 = {r[4], r[5], r[6], r[7]};
        float* rowp = outs + (size_t)(w8 + i) * 512;
        *(f32x4*)(rowp + lane * 4) = w0;          // plain write-back store
        *(f32x4*)(rowp + 256 + lane * 4) = w1;
    }
}

extern "C" void kernel_launch(void* const* d_in, const int* in_sizes, int n_in,
                              void* d_out, int out_size, void* d_ws, size_t ws_size,
                              hipStream_t stream) {
    const float* x   = (const float*)d_in[0];   // (8,64,512,16) fp32
    const float* msk = (const float*)d_in[1];   // (8,64,512,1)  fp32
    float* out = (float*)d_out;                 // (8,64,512,512,1) fp32

    // x = slice, y = row-tile: linear id == slice (mod 8) -> per-slice XCD affinity
    dim3 grid(512, 8);
    node_pair_gaussian_kernel<<<grid, 512, 0, stream>>>(x, msk, out);
}